// Round 1
// baseline (49.126 us; speedup 1.0000x reference)
//
#include <hip/hip_runtime.h>

// Problem constants (from reference): t [32,8192] f32, control_points [22,3,10] f32.
// Outputs: pos, vel, acc each [32,8192,22,3] f32, concatenated flat.
#define NPTS      (32 * 8192)        // 262144 eval points
#define OUT_PER_PT 66                // 22*3
#define TOTF      (NPTS * OUT_PER_PT) // 17,301,504 floats per output tensor
#define PTS_PER_BLOCK 64
#define THREADS   256
#define FD_H      1e-6

// Faithful mirror of the reference _basis() (truncated Cox-de Boor: level r
// computes only indices 0..(10-r-1); tail forced to zero), in float64,
// with knots = np.linspace(0,1,8).astype(float32) padded by 3 on each side.
// Divisions by the (constant, f32-subtracted) knot deltas are folded to
// compile-time reciprocal multiplies.
__device__ __forceinline__ void basis10(double t, double* __restrict__ N) {
    // f32 knot values exactly as numpy produces them (i * (1/7 in f64) -> f32; last = 1.0f)
    const float kf[14] = {
        0.0f, 0.0f, 0.0f, 0.0f,
        (float)(1.0 * (1.0 / 7.0)), (float)(2.0 * (1.0 / 7.0)),
        (float)(3.0 * (1.0 / 7.0)), (float)(4.0 * (1.0 / 7.0)),
        (float)(5.0 * (1.0 / 7.0)), (float)(6.0 * (1.0 / 7.0)),
        1.0f, 1.0f, 1.0f, 1.0f
    };
    double K[14];
#pragma unroll
    for (int i = 0; i < 14; ++i) K[i] = (double)kf[i];

    // degree-0 indicators: knots[i] <= t < knots[i+1]  (handles t<0 and t>=1 -> all zero)
#pragma unroll
    for (int i = 0; i < 10; ++i)
        N[i] = (t >= K[i] && t < K[i + 1]) ? 1.0 : 0.0;

#pragma unroll
    for (int r = 1; r <= 3; ++r) {
#pragma unroll
        for (int i = 0; i < 9; ++i) {
            if (i < 10 - r) {
                const float dlf = kf[i + r] - kf[i];         // f32 delta, like numpy
                const float drf = kf[i + r + 1] - kf[i + 1];
                const double il = (dlf != 0.0f) ? 1.0 / (double)dlf : 0.0;
                const double ir = (drf != 0.0f) ? 1.0 / (double)drf : 0.0;
                N[i] = ((t - K[i]) * il) * N[i] + ((K[i + r + 1] - t) * ir) * N[i + 1];
            }
        }
        N[10 - r] = 0.0;  // reference pads zeros above index m = 10-r
    }
}

__global__ __launch_bounds__(THREADS)
void spline_kernel(const float* __restrict__ t_in,
                   const float* __restrict__ cp_in,
                   float* __restrict__ out) {
    __shared__ __align__(16) float s_cp[660];                       // [22*3][10]
    __shared__ __align__(16) float s_b[PTS_PER_BLOCK][20];          // b0[10] | d1[10]
    __shared__ __align__(16) float s_pos[PTS_PER_BLOCK * OUT_PER_PT];
    __shared__ __align__(16) float s_vel[PTS_PER_BLOCK * OUT_PER_PT];

    const int tid = threadIdx.x;
    const int blk = blockIdx.x;

    // stage control points
    for (int i = tid; i < 660; i += THREADS) s_cp[i] = cp_in[i];

    // Phase 1: one thread per point computes f64 basis + f64 finite difference.
    if (tid < PTS_PER_BLOCK) {
        const int pt = blk * PTS_PER_BLOCK + tid;
        const double t = (double)t_in[pt];
        double Nt[10], Np[10], Nm[10];
        basis10(t, Nt);
        basis10(t + FD_H, Np);
        basis10(t - FD_H, Nm);
#pragma unroll
        for (int i = 0; i < 10; ++i) {
            s_b[tid][i]      = (float)Nt[i];
            s_b[tid][10 + i] = (float)((Np[i] - Nm[i]) / (2.0 * FD_H));
        }
    }
    __syncthreads();

    // Phase 2: 4 threads per point compute the 66 (j,k) dot products each for pos & vel.
    {
        const int p = tid >> 2;
        const int q = tid & 3;
        float b0[10], d1[10];
#pragma unroll
        for (int i = 0; i < 10; ++i) {
            b0[i] = s_b[p][i];
            d1[i] = s_b[p][10 + i];
        }
        for (int jk = q; jk < OUT_PER_PT; jk += 4) {
            float pf = 0.0f, vf = 0.0f;
#pragma unroll
            for (int i = 0; i < 10; ++i) {
                const float c = s_cp[jk * 10 + i];
                pf += b0[i] * c;
                vf += d1[i] * c;
            }
            s_pos[p * OUT_PER_PT + jk] = pf;
            s_vel[p * OUT_PER_PT + jk] = vf;
        }
    }
    __syncthreads();

    // Phase 3: coalesced float4 copy-out. Block region is contiguous in all three outputs.
    {
        const int nf4 = PTS_PER_BLOCK * OUT_PER_PT / 4;  // 1056
        const float4* sp4 = (const float4*)s_pos;
        const float4* sv4 = (const float4*)s_vel;
        float4* op = (float4*)(out + (size_t)blk * (PTS_PER_BLOCK * OUT_PER_PT));
        float4* ov = (float4*)(out + (size_t)TOTF + (size_t)blk * (PTS_PER_BLOCK * OUT_PER_PT));
        float4* oa = (float4*)(out + (size_t)2 * TOTF + (size_t)blk * (PTS_PER_BLOCK * OUT_PER_PT));
        for (int i = tid; i < nf4; i += THREADS) {
            op[i] = sp4[i];
            const float4 v = sv4[i];
            ov[i] = v;
            oa[i] = v;
        }
    }
}

extern "C" void kernel_launch(void* const* d_in, const int* in_sizes, int n_in,
                              void* d_out, int out_size, void* d_ws, size_t ws_size,
                              hipStream_t stream) {
    const float* t_in  = (const float*)d_in[0];   // [32, 8192] f32
    const float* cp_in = (const float*)d_in[1];   // [22, 3, 10] f32
    float* out = (float*)d_out;                   // pos | vel | acc, each [32,8192,22,3] f32

    const int blocks = NPTS / PTS_PER_BLOCK;      // 4096
    spline_kernel<<<blocks, THREADS, 0, stream>>>(t_in, cp_in, out);
}